// Round 1
// baseline (1576.228 us; speedup 1.0000x reference)
//
#include <hip/hip_runtime.h>
#include <math.h>

#define HID 128
#define NN 128      // nodes per graph
#define NB 16       // graphs
#define BN 2048     // total nodes
#define NLAY 4
#define INF 21
#define ONF 20

__device__ __forceinline__ float fsilu(float v) { return v / (1.f + __expf(-v)); }
__device__ __forceinline__ float fsig(float v)  { return 1.f / (1.f + __expf(-v)); }

// ---------------- input embedding: h = h0 @ emb_in_w + b ; x copy ----------------
__global__ void k_embed(const float* __restrict__ h0, const float* __restrict__ x0,
                        const float* __restrict__ w, const float* __restrict__ b,
                        float* __restrict__ h, float* __restrict__ x) {
    __shared__ float hs[INF];
    int n = blockIdx.x, t = threadIdx.x;
    if (t < INF) hs[t] = h0[n * INF + t];
    __syncthreads();
    float acc = b[t];
#pragma unroll
    for (int k = 0; k < INF; ++k) acc += hs[k] * w[k * HID + t];
    h[n * HID + t] = acc;
    if (t < 3) x[n * 3 + t] = x0[n * 3 + t];
}

// ---------------- per-layer node projections: p1 = h@W1a, p2 = h@W1b ----------------
__global__ void k_proj(const float* __restrict__ h, const float* __restrict__ ew1,
                       float* __restrict__ p1, float* __restrict__ p2) {
    __shared__ float hs[HID];
    int n = blockIdx.x, t = threadIdx.x;
    hs[t] = h[n * HID + t];
    __syncthreads();
    float a1 = 0.f, a2 = 0.f;
#pragma unroll 4
    for (int k = 0; k < HID; ++k) {
        float hv = hs[k];
        a1 += hv * ew1[k * HID + t];
        a2 += hv * ew1[(HID + k) * HID + t];
    }
    p1[n * HID + t] = a1;
    p2[n * HID + t] = a2;
}

// ---------------- edge pipeline: one block per destination node i ----------------
// pre[j,:] = p1[i] + p2[j] + radial(i,j)*wr + (w_attr + b1)
// m = silu(silu(pre)@W2 + b2); gate = sigmoid(m@att_w + att_b) (0 for j==i)
// phi[j] = silu(gate*(m@C1) + c1b) @ c2
// m_agg[i] = sum_j gate[j]*m[j,:]; xdel[i] = sum_j cd[j]*phi[j] / 127
__global__ __launch_bounds__(256, 4) void k_edge(
    const float* __restrict__ x, const float* __restrict__ p1g, const float* __restrict__ p2g,
    const float* __restrict__ ew1, const float* __restrict__ eb1,
    const float* __restrict__ w2, const float* __restrict__ b2,
    const float* __restrict__ attw, const float* __restrict__ attbp,
    const float* __restrict__ c1, const float* __restrict__ c1b, const float* __restrict__ c2,
    float* __restrict__ magg, float* __restrict__ xdel) {
    __shared__ float S[64 * 129];   // silu(pre) then m, half of j at a time
    __shared__ float cds[NN * 3];
    __shared__ float rad[NN];
    __shared__ float rowdot[64];
    __shared__ float gatev[64];
    __shared__ float phis[64];

    const int i = blockIdx.x;
    const int g = i >> 7, base = g << 7;
    const int tid = threadIdx.x;
    const int t = tid & 127, jh = tid >> 7;        // pre / m_agg mapping
    const int tj = tid >> 5, tt = tid & 31;        // GEMM tile: rows tj*8..+7, cols tt*4..+3

    const float xi0 = x[i * 3 + 0], xi1 = x[i * 3 + 1], xi2 = x[i * 3 + 2];
    if (tid < NN) {
        int j = base + tid;
        float d0 = xi0 - x[j * 3 + 0], d1 = xi1 - x[j * 3 + 1], d2 = xi2 - x[j * 3 + 2];
        cds[tid * 3 + 0] = d0; cds[tid * 3 + 1] = d1; cds[tid * 3 + 2] = d2;
        rad[tid] = d0 * d0 + d1 * d1 + d2 * d2;
    }
    const float p1v = p1g[i * HID + t];
    const float wrv = ew1[256 * HID + t];
    const float bcv = ew1[257 * HID + t] + eb1[t];
    const float attb = attbp[0];

    const float b2v0 = b2[tt * 4 + 0], b2v1 = b2[tt * 4 + 1], b2v2 = b2[tt * 4 + 2], b2v3 = b2[tt * 4 + 3];
    const float aw0 = attw[tt * 4 + 0], aw1 = attw[tt * 4 + 1], aw2 = attw[tt * 4 + 2], aw3 = attw[tt * 4 + 3];
    const float cb0 = c1b[tt * 4 + 0], cb1 = c1b[tt * 4 + 1], cb2 = c1b[tt * 4 + 2], cb3 = c1b[tt * 4 + 3];
    const float cw0 = c2[tt * 4 + 0], cw1 = c2[tt * 4 + 1], cw2 = c2[tt * 4 + 2], cw3 = c2[tt * 4 + 3];

    float magg_acc = 0.f;
    float xa0 = 0.f, xa1 = 0.f, xa2 = 0.f;

    for (int half = 0; half < 2; ++half) {
        const int jb = half * 64;
        __syncthreads();   // prev-half S reads done; rad/cds ready (half 0)
        for (int jj = jh; jj < 64; jj += 2) {
            int j = base + jb + jj;
            float pre = p1v + p2g[j * HID + t] + rad[jb + jj] * wrv + bcv;
            S[jj * 129 + t] = fsilu(pre);
        }
        __syncthreads();

        // GEMM1: acc = S @ W2  (64x128 out, 8x4 per thread)
        float acc[8][4];
#pragma unroll
        for (int r = 0; r < 8; ++r) { acc[r][0] = 0.f; acc[r][1] = 0.f; acc[r][2] = 0.f; acc[r][3] = 0.f; }
        for (int k = 0; k < HID; ++k) {
            float a[8];
#pragma unroll
            for (int r = 0; r < 8; ++r) a[r] = S[(tj * 8 + r) * 129 + k];
            float4 bv = *reinterpret_cast<const float4*>(&w2[k * HID + tt * 4]);
#pragma unroll
            for (int r = 0; r < 8; ++r) {
                acc[r][0] += a[r] * bv.x; acc[r][1] += a[r] * bv.y;
                acc[r][2] += a[r] * bv.z; acc[r][3] += a[r] * bv.w;
            }
        }
        __syncthreads();   // S fully consumed, safe to overwrite with m

        // m = silu(acc + b2); write to S; attention partial dot
        float patt[8];
#pragma unroll
        for (int r = 0; r < 8; ++r) {
            float m0 = fsilu(acc[r][0] + b2v0), m1 = fsilu(acc[r][1] + b2v1);
            float m2 = fsilu(acc[r][2] + b2v2), m3 = fsilu(acc[r][3] + b2v3);
            int ro = (tj * 8 + r) * 129 + tt * 4;
            S[ro + 0] = m0; S[ro + 1] = m1; S[ro + 2] = m2; S[ro + 3] = m3;
            patt[r] = m0 * aw0 + m1 * aw1 + m2 * aw2 + m3 * aw3;
        }
#pragma unroll
        for (int off = 16; off >= 1; off >>= 1) {
#pragma unroll
            for (int r = 0; r < 8; ++r) patt[r] += __shfl_xor(patt[r], off, 64);
        }
        if (tt == 0) {
#pragma unroll
            for (int r = 0; r < 8; ++r) rowdot[tj * 8 + r] = patt[r];
        }
        __syncthreads();
        if (tid < 64) {
            int j = jb + tid;
            gatev[tid] = (base + j == i) ? 0.f : fsig(rowdot[tid] + attb);
        }
        __syncthreads();

        // GEMM2: acc2 = m @ C1
        float acc2[8][4];
#pragma unroll
        for (int r = 0; r < 8; ++r) { acc2[r][0] = 0.f; acc2[r][1] = 0.f; acc2[r][2] = 0.f; acc2[r][3] = 0.f; }
        for (int k = 0; k < HID; ++k) {
            float a[8];
#pragma unroll
            for (int r = 0; r < 8; ++r) a[r] = S[(tj * 8 + r) * 129 + k];
            float4 bv = *reinterpret_cast<const float4*>(&c1[k * HID + tt * 4]);
#pragma unroll
            for (int r = 0; r < 8; ++r) {
                acc2[r][0] += a[r] * bv.x; acc2[r][1] += a[r] * bv.y;
                acc2[r][2] += a[r] * bv.z; acc2[r][3] += a[r] * bv.w;
            }
        }
        // phi partial: silu(gate * acc2 + c1b) . c2
        float pp[8];
#pragma unroll
        for (int r = 0; r < 8; ++r) {
            float gr = gatev[tj * 8 + r];
            pp[r] = fsilu(gr * acc2[r][0] + cb0) * cw0 + fsilu(gr * acc2[r][1] + cb1) * cw1 +
                    fsilu(gr * acc2[r][2] + cb2) * cw2 + fsilu(gr * acc2[r][3] + cb3) * cw3;
        }
#pragma unroll
        for (int off = 16; off >= 1; off >>= 1) {
#pragma unroll
            for (int r = 0; r < 8; ++r) pp[r] += __shfl_xor(pp[r], off, 64);
        }
        if (tt == 0) {
#pragma unroll
            for (int r = 0; r < 8; ++r) phis[tj * 8 + r] = pp[r];
        }
        __syncthreads();

        // m_agg partial (m still in S), and coord delta partial
        for (int jj = jh; jj < 64; jj += 2) magg_acc += gatev[jj] * S[jj * 129 + t];
        if (tid < 64) {
            int j = jb + tid;
            float ph = phis[tid];
            xa0 += cds[j * 3 + 0] * ph; xa1 += cds[j * 3 + 1] * ph; xa2 += cds[j * 3 + 2] * ph;
        }
    }
    __syncthreads();
    S[tid] = magg_acc;                                   // reuse S as scratch
    if (tid < 64) { cds[tid * 3 + 0] = xa0; cds[tid * 3 + 1] = xa1; cds[tid * 3 + 2] = xa2; }
    __syncthreads();
    if (tid < HID) magg[i * HID + tid] = S[tid] + S[tid + 128];
    if (tid < 3) {
        float s = 0.f;
        for (int j = 0; j < 64; ++j) s += cds[j * 3 + tid];
        xdel[i * 3 + tid] = s * (1.f / 127.f);
    }
}

// ---------------- node update + coord apply ----------------
__global__ void k_node(float* __restrict__ h, float* __restrict__ x,
                       const float* __restrict__ magg, const float* __restrict__ xdel,
                       const float* __restrict__ nw1, const float* __restrict__ nb1,
                       const float* __restrict__ nw2, const float* __restrict__ nb2) {
    __shared__ float hs[HID], ms[HID], dhs[HID];
    int n = blockIdx.x, t = threadIdx.x;
    hs[t] = h[n * HID + t];
    ms[t] = magg[n * HID + t];
    __syncthreads();
    float acc = nb1[t];
#pragma unroll 4
    for (int k = 0; k < HID; ++k)
        acc += hs[k] * nw1[k * HID + t] + ms[k] * nw1[(HID + k) * HID + t];
    dhs[t] = fsilu(acc);
    __syncthreads();
    float a2 = nb2[t];
#pragma unroll 4
    for (int k = 0; k < HID; ++k) a2 += dhs[k] * nw2[k * HID + t];
    h[n * HID + t] = hs[t] + a2;
    if (t < 3) x[n * 3 + t] += xdel[n * 3 + t];
}

// ---------------- output embedding ----------------
__global__ void k_embout(const float* __restrict__ h, const float* __restrict__ w,
                         const float* __restrict__ b, float* __restrict__ hout) {
    __shared__ float hs[HID];
    int n = blockIdx.x, t = threadIdx.x;
    hs[t] = h[n * HID + t];
    __syncthreads();
    float acc = b[t];
#pragma unroll 4
    for (int k = 0; k < HID; ++k) acc += hs[k] * w[k * HID + t];
    hout[n * HID + t] = acc;
}

// ---------------- per-graph mean pool ----------------
__global__ void k_pool(const float* __restrict__ he, float* __restrict__ hp) {
    int gph = blockIdx.x, t = threadIdx.x;
    float s = 0.f;
    for (int j = 0; j < NN; ++j) s += he[(gph * NN + j) * HID + t];
    hp[gph * HID + t] = s * (1.f / 128.f);
}

// ---------------- head MLP ----------------
__global__ void k_head(const float* __restrict__ hp, const float* __restrict__ w1,
                       const float* __restrict__ b1, const float* __restrict__ w2,
                       const float* __restrict__ b2, float* __restrict__ out) {
    __shared__ float hs[HID], rs[HID];
    int gph = blockIdx.x, t = threadIdx.x;
    hs[t] = hp[gph * HID + t];
    __syncthreads();
    float acc = b1[t];
#pragma unroll 4
    for (int k = 0; k < HID; ++k) acc += hs[k] * w1[k * HID + t];
    rs[t] = fmaxf(acc, 0.f);
    __syncthreads();
    if (t < ONF) {
        float a = b2[t];
        for (int k = 0; k < HID; ++k) a += rs[k] * w2[k * ONF + t];
        out[gph * ONF + t] = a;
    }
}

extern "C" void kernel_launch(void* const* d_in, const int* in_sizes, int n_in,
                              void* d_out, int out_size, void* d_ws, size_t ws_size,
                              hipStream_t stream) {
    const float* h0        = (const float*)d_in[0];
    const float* x0        = (const float*)d_in[1];
    const float* emb_in_w  = (const float*)d_in[2];
    const float* emb_in_b  = (const float*)d_in[3];
    const float* edge_w1   = (const float*)d_in[4];
    const float* edge_b1   = (const float*)d_in[5];
    const float* edge_w2   = (const float*)d_in[6];
    const float* edge_b2   = (const float*)d_in[7];
    const float* att_w     = (const float*)d_in[8];
    const float* att_b     = (const float*)d_in[9];
    const float* node_w1   = (const float*)d_in[10];
    const float* node_b1   = (const float*)d_in[11];
    const float* node_w2   = (const float*)d_in[12];
    const float* node_b2   = (const float*)d_in[13];
    const float* coord_w1  = (const float*)d_in[14];
    const float* coord_b1  = (const float*)d_in[15];
    const float* coord_w2  = (const float*)d_in[16];
    const float* emb_out_w = (const float*)d_in[17];
    const float* emb_out_b = (const float*)d_in[18];
    const float* head_w1   = (const float*)d_in[19];
    const float* head_b1   = (const float*)d_in[20];
    const float* head_w2   = (const float*)d_in[21];
    const float* head_b2   = (const float*)d_in[22];

    float* ws    = (float*)d_ws;
    float* h_cur = ws;                   // BN*HID
    float* p1    = h_cur + BN * HID;     // BN*HID (reused as h_emb at the end)
    float* p2    = p1 + BN * HID;        // BN*HID (reused as h_pool at the end)
    float* magg  = p2 + BN * HID;        // BN*HID
    float* xc    = magg + BN * HID;      // BN*3
    float* xdel  = xc + BN * 3;          // BN*3

    k_embed<<<BN, HID, 0, stream>>>(h0, x0, emb_in_w, emb_in_b, h_cur, xc);
    for (int l = 0; l < NLAY; ++l) {
        k_proj<<<BN, HID, 0, stream>>>(h_cur, edge_w1 + (size_t)l * 258 * HID, p1, p2);
        k_edge<<<BN, 256, 0, stream>>>(xc, p1, p2,
            edge_w1 + (size_t)l * 258 * HID, edge_b1 + l * HID,
            edge_w2 + (size_t)l * HID * HID, edge_b2 + l * HID,
            att_w + l * HID, att_b + l,
            coord_w1 + (size_t)l * HID * HID, coord_b1 + l * HID, coord_w2 + l * HID,
            magg, xdel);
        k_node<<<BN, HID, 0, stream>>>(h_cur, xc, magg, xdel,
            node_w1 + (size_t)l * 2 * HID * HID, node_b1 + l * HID,
            node_w2 + (size_t)l * HID * HID, node_b2 + l * HID);
    }
    k_embout<<<BN, HID, 0, stream>>>(h_cur, emb_out_w, emb_out_b, p1);
    k_pool<<<NB, HID, 0, stream>>>(p1, p2);
    k_head<<<NB, HID, 0, stream>>>(p2, head_w1, head_b1, head_w2, head_b2, (float*)d_out);
}

// Round 2
// 472.876 us; speedup vs baseline: 3.3333x; 3.3333x over previous
//
#include <hip/hip_runtime.h>
#include <math.h>

#define HID 128
#define NN 128      // nodes per graph
#define NB 16       // graphs
#define BN 2048     // total nodes
#define NLAY 4
#define INF 21
#define ONF 20
#define SPAD 136    // padded LDS row stride in bf16 elems (272B -> conflict-free b128)

typedef __attribute__((ext_vector_type(8))) short bf16x8;
typedef __attribute__((ext_vector_type(4))) float f32x4;

__device__ __forceinline__ float fsilu(float v) { return v / (1.f + __expf(-v)); }
__device__ __forceinline__ float fsig(float v)  { return 1.f / (1.f + __expf(-v)); }
__device__ __forceinline__ unsigned short f2bf(float f) {   // RNE fp32->bf16
    union { float f; unsigned u; } v; v.f = f;
    unsigned r = v.u + 0x7fffu + ((v.u >> 16) & 1u);
    return (unsigned short)(r >> 16);
}
__device__ __forceinline__ float bf2f(unsigned short u) {
    union { unsigned u; float f; } v; v.u = ((unsigned)u) << 16;
    return v.f;
}

// ---------------- weight pack: 8 matrices (edge_w2 x4, coord_w1 x4) -> bf16 B-fragments ----------
// fragment entry e (global): matrix m=e>>11, f=e&2047: n=f>>8 (col tile), kk=(f>>6)&3, l=f&63.
// lane l holds B[k=kk*32+(l>>4)*8+j][col=n*16+(l&15)], j=0..7, stored contiguously (16B/lane).
__global__ void k_pack(const float* __restrict__ w2, const float* __restrict__ c1,
                       unsigned short* __restrict__ out) {
    int e = blockIdx.x * 256 + threadIdx.x;   // 64 blocks * 256 = 16384 entries
    int m = e >> 11;
    int f = e & 2047;
    int l = f & 63, kk = (f >> 6) & 3, n = f >> 8;
    const float* w = (m < 4) ? (w2 + (size_t)m * HID * HID) : (c1 + (size_t)(m - 4) * HID * HID);
    int col = n * 16 + (l & 15);
    int k0 = kk * 32 + (l >> 4) * 8;
    unsigned short tmp[8];
#pragma unroll
    for (int j = 0; j < 8; ++j) tmp[j] = f2bf(w[(size_t)(k0 + j) * HID + col]);
    *(bf16x8*)(out + (size_t)e * 8) = *(const bf16x8*)tmp;
}

// ---------------- input embedding ----------------
__global__ void k_embed(const float* __restrict__ h0, const float* __restrict__ x0,
                        const float* __restrict__ w, const float* __restrict__ b,
                        float* __restrict__ h, float* __restrict__ x) {
    __shared__ float hs[INF];
    int n = blockIdx.x, t = threadIdx.x;
    if (t < INF) hs[t] = h0[n * INF + t];
    __syncthreads();
    float acc = b[t];
#pragma unroll
    for (int k = 0; k < INF; ++k) acc += hs[k] * w[k * HID + t];
    h[n * HID + t] = acc;
    if (t < 3) x[n * 3 + t] = x0[n * 3 + t];
}

// ---------------- per-layer node projections: p1 = h@W1a, p2 = h@W1b ----------------
__global__ void k_proj(const float* __restrict__ h, const float* __restrict__ ew1,
                       float* __restrict__ p1, float* __restrict__ p2) {
    __shared__ float hs[HID];
    int n = blockIdx.x, t = threadIdx.x;
    hs[t] = h[n * HID + t];
    __syncthreads();
    float a1 = 0.f, a2 = 0.f;
#pragma unroll 4
    for (int k = 0; k < HID; ++k) {
        float hv = hs[k];
        a1 += hv * ew1[k * HID + t];
        a2 += hv * ew1[(HID + k) * HID + t];
    }
    p1[n * HID + t] = a1;
    p2[n * HID + t] = a2;
}

// ---------------- edge pipeline (MFMA): one block per destination node i ----------------
__global__ __launch_bounds__(256, 4) void k_edge(
    const float* __restrict__ x, const float* __restrict__ p1g, const float* __restrict__ p2g,
    const float* __restrict__ ew1, const float* __restrict__ eb1,
    const unsigned short* __restrict__ w2p, const float* __restrict__ b2,
    const float* __restrict__ attw, const float* __restrict__ attbp,
    const unsigned short* __restrict__ c1p, const float* __restrict__ c1b, const float* __restrict__ c2,
    float* __restrict__ magg, float* __restrict__ xdel) {
    __shared__ unsigned short S[128 * SPAD];   // silu(pre) then m, bf16
    __shared__ float cds[NN * 3];
    __shared__ float rad[NN];
    __shared__ float gatev[NN];
    __shared__ float phis[NN];
    __shared__ float red[256];

    const int i = blockIdx.x;
    const int base = (i >> 7) << 7;
    const int tid = threadIdx.x;
    const int lane = tid & 63;
    const int wv = tid >> 6;             // wave 0..3
    const int rowbase = wv * 32;         // this wave owns rows rowbase..rowbase+31
    const int lc = lane & 15;            // col within 16x16 tile
    const int lg = lane >> 4;            // lane group 0..3

    // ---- phase 0: coord diffs + radial ----
    const float xi0 = x[i * 3 + 0], xi1 = x[i * 3 + 1], xi2 = x[i * 3 + 2];
    if (tid < NN) {
        int j = base + tid;
        float d0 = xi0 - x[j * 3 + 0], d1 = xi1 - x[j * 3 + 1], d2 = xi2 - x[j * 3 + 2];
        cds[tid * 3 + 0] = d0; cds[tid * 3 + 1] = d1; cds[tid * 3 + 2] = d2;
        rad[tid] = d0 * d0 + d1 * d1 + d2 * d2;
    }
    __syncthreads();

    // ---- S = silu(pre) in bf16, [128][SPAD] ----
    {
        const int t0 = (tid & 31) * 4;
        const int r0 = tid >> 5;
        const float4 p1v = *(const float4*)(p1g + (size_t)i * HID + t0);
        const float4 wrv = *(const float4*)(ew1 + 256 * HID + t0);
        float4 bcv = *(const float4*)(ew1 + 257 * HID + t0);
        const float4 ebv = *(const float4*)(eb1 + t0);
        bcv.x += ebv.x; bcv.y += ebv.y; bcv.z += ebv.z; bcv.w += ebv.w;
#pragma unroll
        for (int it = 0; it < 16; ++it) {
            int jr = r0 + it * 8;
            float rv = rad[jr];
            const float4 p2v = *(const float4*)(p2g + (size_t)(base + jr) * HID + t0);
            unsigned s0 = f2bf(fsilu(p1v.x + p2v.x + rv * wrv.x + bcv.x));
            unsigned s1 = f2bf(fsilu(p1v.y + p2v.y + rv * wrv.y + bcv.y));
            unsigned s2 = f2bf(fsilu(p1v.z + p2v.z + rv * wrv.z + bcv.z));
            unsigned s3 = f2bf(fsilu(p1v.w + p2v.w + rv * wrv.w + bcv.w));
            uint2 pk; pk.x = s0 | (s1 << 16); pk.y = s2 | (s3 << 16);
            *(uint2*)(S + jr * SPAD + t0) = pk;
        }
    }
    __syncthreads();

    // ---- GEMM1: acc = S @ W2 (wave: rows rowbase..+31 x all 128 cols) ----
    f32x4 acc[2][8];
#pragma unroll
    for (int rt = 0; rt < 2; ++rt)
#pragma unroll
        for (int n = 0; n < 8; ++n) acc[rt][n] = (f32x4){0.f, 0.f, 0.f, 0.f};
#pragma unroll
    for (int kk = 0; kk < 4; ++kk) {
        bf16x8 a0 = *(const bf16x8*)&S[(rowbase + lc) * SPAD + kk * 32 + lg * 8];
        bf16x8 a1 = *(const bf16x8*)&S[(rowbase + 16 + lc) * SPAD + kk * 32 + lg * 8];
#pragma unroll
        for (int n = 0; n < 8; ++n) {
            bf16x8 b = *(const bf16x8*)(w2p + (size_t)((n * 4 + kk) * 64 + lane) * 8);
            acc[0][n] = __builtin_amdgcn_mfma_f32_16x16x32_bf16(a0, b, acc[0][n], 0, 0, 0);
            acc[1][n] = __builtin_amdgcn_mfma_f32_16x16x32_bf16(a1, b, acc[1][n], 0, 0, 0);
        }
    }

    // ---- m = silu(acc + b2) -> S (bf16, own rows); attention partials ----
    float patt[2][4] = {{0.f, 0.f, 0.f, 0.f}, {0.f, 0.f, 0.f, 0.f}};
#pragma unroll
    for (int n = 0; n < 8; ++n) {
        int col = n * 16 + lc;
        float b2v = b2[col];
        float awv = attw[col];
#pragma unroll
        for (int rt = 0; rt < 2; ++rt)
#pragma unroll
            for (int r = 0; r < 4; ++r) {
                float mv = fsilu(acc[rt][n][r] + b2v);
                S[(rowbase + rt * 16 + lg * 4 + r) * SPAD + col] = f2bf(mv);
                patt[rt][r] += mv * awv;
            }
    }
#pragma unroll
    for (int off = 1; off <= 8; off <<= 1)
#pragma unroll
        for (int rt = 0; rt < 2; ++rt)
#pragma unroll
            for (int r = 0; r < 4; ++r)
                patt[rt][r] += __shfl_xor(patt[rt][r], off, 64);
    {
        const float attb = attbp[0];
        if (lc == 0) {
#pragma unroll
            for (int rt = 0; rt < 2; ++rt)
#pragma unroll
                for (int r = 0; r < 4; ++r) {
                    int row = rowbase + rt * 16 + lg * 4 + r;
                    gatev[row] = (base + row == i) ? 0.f : fsig(patt[rt][r] + attb);
                }
        }
    }

    // ---- GEMM2: acc2 = m @ C1 (same rows; within-wave LDS ordering) ----
    f32x4 acc2[2][8];
#pragma unroll
    for (int rt = 0; rt < 2; ++rt)
#pragma unroll
        for (int n = 0; n < 8; ++n) acc2[rt][n] = (f32x4){0.f, 0.f, 0.f, 0.f};
#pragma unroll
    for (int kk = 0; kk < 4; ++kk) {
        bf16x8 a0 = *(const bf16x8*)&S[(rowbase + lc) * SPAD + kk * 32 + lg * 8];
        bf16x8 a1 = *(const bf16x8*)&S[(rowbase + 16 + lc) * SPAD + kk * 32 + lg * 8];
#pragma unroll
        for (int n = 0; n < 8; ++n) {
            bf16x8 b = *(const bf16x8*)(c1p + (size_t)((n * 4 + kk) * 64 + lane) * 8);
            acc2[0][n] = __builtin_amdgcn_mfma_f32_16x16x32_bf16(a0, b, acc2[0][n], 0, 0, 0);
            acc2[1][n] = __builtin_amdgcn_mfma_f32_16x16x32_bf16(a1, b, acc2[1][n], 0, 0, 0);
        }
    }

    // ---- phi = silu(gate*acc2 + c1b) @ c2, reduced over cols ----
    {
        float gv[2][4];
#pragma unroll
        for (int rt = 0; rt < 2; ++rt)
#pragma unroll
            for (int r = 0; r < 4; ++r) gv[rt][r] = gatev[rowbase + rt * 16 + lg * 4 + r];
        float pp[2][4] = {{0.f, 0.f, 0.f, 0.f}, {0.f, 0.f, 0.f, 0.f}};
#pragma unroll
        for (int n = 0; n < 8; ++n) {
            int col = n * 16 + lc;
            float cbv = c1b[col], cwv = c2[col];
#pragma unroll
            for (int rt = 0; rt < 2; ++rt)
#pragma unroll
                for (int r = 0; r < 4; ++r)
                    pp[rt][r] += fsilu(gv[rt][r] * acc2[rt][n][r] + cbv) * cwv;
        }
#pragma unroll
        for (int off = 1; off <= 8; off <<= 1)
#pragma unroll
            for (int rt = 0; rt < 2; ++rt)
#pragma unroll
                for (int r = 0; r < 4; ++r)
                    pp[rt][r] += __shfl_xor(pp[rt][r], off, 64);
        if (lc == 0) {
#pragma unroll
            for (int rt = 0; rt < 2; ++rt)
#pragma unroll
                for (int r = 0; r < 4; ++r)
                    phis[rowbase + rt * 16 + lg * 4 + r] = pp[rt][r];
        }
    }
    __syncthreads();

    // ---- m_agg = sum_j gate[j]*m[j][:]; coord-delta partials ----
    {
        const int t = tid & 127, jh = tid >> 7;
        float macc = 0.f;
        for (int j = jh; j < NN; j += 2)
            macc += gatev[j] * bf2f(S[j * SPAD + t]);
        red[tid] = macc;
        if (tid < NN) {
            float ph = phis[tid];
            cds[tid * 3 + 0] *= ph; cds[tid * 3 + 1] *= ph; cds[tid * 3 + 2] *= ph;
        }
    }
    __syncthreads();
    if (tid < HID) magg[(size_t)i * HID + tid] = red[tid] + red[tid + 128];
    if (tid < 3) {
        float s = 0.f;
        for (int j = 0; j < NN; ++j) s += cds[j * 3 + tid];
        xdel[i * 3 + tid] = s * (1.f / 127.f);
    }
}

// ---------------- node update + coord apply ----------------
__global__ void k_node(float* __restrict__ h, float* __restrict__ x,
                       const float* __restrict__ magg, const float* __restrict__ xdel,
                       const float* __restrict__ nw1, const float* __restrict__ nb1,
                       const float* __restrict__ nw2, const float* __restrict__ nb2) {
    __shared__ float hs[HID], ms[HID], dhs[HID];
    int n = blockIdx.x, t = threadIdx.x;
    hs[t] = h[n * HID + t];
    ms[t] = magg[n * HID + t];
    __syncthreads();
    float acc = nb1[t];
#pragma unroll 4
    for (int k = 0; k < HID; ++k)
        acc += hs[k] * nw1[k * HID + t] + ms[k] * nw1[(HID + k) * HID + t];
    dhs[t] = fsilu(acc);
    __syncthreads();
    float a2 = nb2[t];
#pragma unroll 4
    for (int k = 0; k < HID; ++k) a2 += dhs[k] * nw2[k * HID + t];
    h[n * HID + t] = hs[t] + a2;
    if (t < 3) x[n * 3 + t] += xdel[n * 3 + t];
}

// ---------------- output embedding ----------------
__global__ void k_embout(const float* __restrict__ h, const float* __restrict__ w,
                         const float* __restrict__ b, float* __restrict__ hout) {
    __shared__ float hs[HID];
    int n = blockIdx.x, t = threadIdx.x;
    hs[t] = h[n * HID + t];
    __syncthreads();
    float acc = b[t];
#pragma unroll 4
    for (int k = 0; k < HID; ++k) acc += hs[k] * w[k * HID + t];
    hout[n * HID + t] = acc;
}

// ---------------- per-graph mean pool ----------------
__global__ void k_pool(const float* __restrict__ he, float* __restrict__ hp) {
    int gph = blockIdx.x, t = threadIdx.x;
    float s = 0.f;
    for (int j = 0; j < NN; ++j) s += he[(gph * NN + j) * HID + t];
    hp[gph * HID + t] = s * (1.f / 128.f);
}

// ---------------- head MLP ----------------
__global__ void k_head(const float* __restrict__ hp, const float* __restrict__ w1,
                       const float* __restrict__ b1, const float* __restrict__ w2,
                       const float* __restrict__ b2, float* __restrict__ out) {
    __shared__ float hs[HID], rs[HID];
    int gph = blockIdx.x, t = threadIdx.x;
    hs[t] = hp[gph * HID + t];
    __syncthreads();
    float acc = b1[t];
#pragma unroll 4
    for (int k = 0; k < HID; ++k) acc += hs[k] * w1[k * HID + t];
    rs[t] = fmaxf(acc, 0.f);
    __syncthreads();
    if (t < ONF) {
        float a = b2[t];
        for (int k = 0; k < HID; ++k) a += rs[k] * w2[k * ONF + t];
        out[gph * ONF + t] = a;
    }
}

extern "C" void kernel_launch(void* const* d_in, const int* in_sizes, int n_in,
                              void* d_out, int out_size, void* d_ws, size_t ws_size,
                              hipStream_t stream) {
    const float* h0        = (const float*)d_in[0];
    const float* x0        = (const float*)d_in[1];
    const float* emb_in_w  = (const float*)d_in[2];
    const float* emb_in_b  = (const float*)d_in[3];
    const float* edge_w1   = (const float*)d_in[4];
    const float* edge_b1   = (const float*)d_in[5];
    const float* edge_w2   = (const float*)d_in[6];
    const float* edge_b2   = (const float*)d_in[7];
    const float* att_w     = (const float*)d_in[8];
    const float* att_b     = (const float*)d_in[9];
    const float* node_w1   = (const float*)d_in[10];
    const float* node_b1   = (const float*)d_in[11];
    const float* node_w2   = (const float*)d_in[12];
    const float* node_b2   = (const float*)d_in[13];
    const float* coord_w1  = (const float*)d_in[14];
    const float* coord_b1  = (const float*)d_in[15];
    const float* coord_w2  = (const float*)d_in[16];
    const float* emb_out_w = (const float*)d_in[17];
    const float* emb_out_b = (const float*)d_in[18];
    const float* head_w1   = (const float*)d_in[19];
    const float* head_b1   = (const float*)d_in[20];
    const float* head_w2   = (const float*)d_in[21];
    const float* head_b2   = (const float*)d_in[22];

    float* ws    = (float*)d_ws;
    float* h_cur = ws;                   // BN*HID
    float* p1    = h_cur + BN * HID;     // BN*HID (reused as h_emb at the end)
    float* p2    = p1 + BN * HID;        // BN*HID (reused as h_pool at the end)
    float* magg  = p2 + BN * HID;        // BN*HID
    float* xc    = magg + BN * HID;      // BN*3
    float* xdel  = xc + BN * 3;          // BN*3
    unsigned short* wpack = (unsigned short*)(xdel + BN * 3);  // 8 * 16384 bf16

    k_pack<<<64, 256, 0, stream>>>(edge_w2, coord_w1, wpack);
    k_embed<<<BN, HID, 0, stream>>>(h0, x0, emb_in_w, emb_in_b, h_cur, xc);
    for (int l = 0; l < NLAY; ++l) {
        k_proj<<<BN, HID, 0, stream>>>(h_cur, edge_w1 + (size_t)l * 258 * HID, p1, p2);
        k_edge<<<BN, 256, 0, stream>>>(xc, p1, p2,
            edge_w1 + (size_t)l * 258 * HID, edge_b1 + l * HID,
            wpack + (size_t)l * HID * HID, edge_b2 + l * HID,
            att_w + l * HID, att_b + l,
            wpack + (size_t)(4 + l) * HID * HID, coord_b1 + l * HID, coord_w2 + l * HID,
            magg, xdel);
        k_node<<<BN, HID, 0, stream>>>(h_cur, xc, magg, xdel,
            node_w1 + (size_t)l * 2 * HID * HID, node_b1 + l * HID,
            node_w2 + (size_t)l * HID * HID, node_b2 + l * HID);
    }
    k_embout<<<BN, HID, 0, stream>>>(h_cur, emb_out_w, emb_out_b, p1);
    k_pool<<<NB, HID, 0, stream>>>(p1, p2);
    k_head<<<NB, HID, 0, stream>>>(p2, head_w1, head_b1, head_w2, head_b2, (float*)d_out);
}

// Round 3
// 413.689 us; speedup vs baseline: 3.8102x; 1.1431x over previous
//
#include <hip/hip_runtime.h>
#include <math.h>

#define HID 128
#define NN 128      // nodes per graph
#define NB 16       // graphs
#define BN 2048     // total nodes
#define NLAY 4
#define INF 21
#define ONF 20
#define SPAD 136    // padded LDS row stride in bf16 elems

typedef __attribute__((ext_vector_type(8))) short bf16x8;
typedef __attribute__((ext_vector_type(4))) float f32x4;

__device__ __forceinline__ float fsilu(float v) { return v / (1.f + __expf(-v)); }
__device__ __forceinline__ float fsig(float v)  { return 1.f / (1.f + __expf(-v)); }
__device__ __forceinline__ unsigned short f2bf(float f) {   // RNE fp32->bf16
    union { float f; unsigned u; } v; v.f = f;
    unsigned r = v.u + 0x7fffu + ((v.u >> 16) & 1u);
    return (unsigned short)(r >> 16);
}
__device__ __forceinline__ float bf2f(unsigned short u) {
    union { unsigned u; float f; } v; v.u = ((unsigned)u) << 16;
    return v.f;
}

// ---------------- weight pack: 8 matrices (edge_w2 x4, coord_w1 x4) -> bf16 fragments ----------
// entry e: matrix m=e>>11, f=e&2047: n=f>>8 (tile), kk=(f>>6)&3, l=f&63.
// lane l holds W[k=kk*32+(l>>4)*8+j][n*16+(l&15)], j=0..7  == A-fragment of W^T (row-tile n, k-blk kk)
__global__ void k_pack(const float* __restrict__ w2, const float* __restrict__ c1,
                       unsigned short* __restrict__ out) {
    int e = blockIdx.x * 256 + threadIdx.x;   // 64 blocks * 256 = 16384 entries
    int m = e >> 11;
    int f = e & 2047;
    int l = f & 63, kk = (f >> 6) & 3, n = f >> 8;
    const float* w = (m < 4) ? (w2 + (size_t)m * HID * HID) : (c1 + (size_t)(m - 4) * HID * HID);
    int col = n * 16 + (l & 15);
    int k0 = kk * 32 + (l >> 4) * 8;
    unsigned short tmp[8];
#pragma unroll
    for (int j = 0; j < 8; ++j) tmp[j] = f2bf(w[(size_t)(k0 + j) * HID + col]);
    *(bf16x8*)(out + (size_t)e * 8) = *(const bf16x8*)tmp;
}

// ---------------- input embedding ----------------
__global__ void k_embed(const float* __restrict__ h0, const float* __restrict__ x0,
                        const float* __restrict__ w, const float* __restrict__ b,
                        float* __restrict__ h, float* __restrict__ x) {
    __shared__ float hs[INF];
    int n = blockIdx.x, t = threadIdx.x;
    if (t < INF) hs[t] = h0[n * INF + t];
    __syncthreads();
    float acc = b[t];
#pragma unroll
    for (int k = 0; k < INF; ++k) acc += hs[k] * w[k * HID + t];
    h[n * HID + t] = acc;
    if (t < 3) x[n * 3 + t] = x0[n * 3 + t];
}

// ---------------- per-layer node projections: p1 = h@W1a, p2 = h@W1b ----------------
__global__ void k_proj(const float* __restrict__ h, const float* __restrict__ ew1,
                       float* __restrict__ p1, float* __restrict__ p2) {
    __shared__ float hs[HID];
    int n = blockIdx.x, t = threadIdx.x;
    hs[t] = h[n * HID + t];
    __syncthreads();
    float a1 = 0.f, a2 = 0.f;
#pragma unroll 4
    for (int k = 0; k < HID; ++k) {
        float hv = hs[k];
        a1 += hv * ew1[k * HID + t];
        a2 += hv * ew1[(HID + k) * HID + t];
    }
    p1[n * HID + t] = a1;
    p2[n * HID + t] = a2;
}

// ---------------- edge pipeline (swapped-operand MFMA): one block per node i ----------------
// GEMM1: P = W2^T @ S^T  -> P[c][j] ; lane owns col j = wv*32 + jt*16 + lc, rows c spread over lg,r
// epilogue: m=silu(P+b2[c]); gate via 2 shfl; mg=gate*m -> S rows (b64 writes)
// GEMM2: E2 = C1^T @ mg^T ; phi[j] = sum_c' silu(E2+c1b)*c2  via per-lane sum + 2 shfl
// m_agg = column-sum of mg (vectorized LDS re-read)
__global__ __launch_bounds__(256, 4) void k_edge(
    const float* __restrict__ x, const float* __restrict__ p1g, const float* __restrict__ p2g,
    const float* __restrict__ ew1, const float* __restrict__ eb1,
    const unsigned short* __restrict__ w2p, const float* __restrict__ b2,
    const float* __restrict__ attw, const float* __restrict__ attbp,
    const unsigned short* __restrict__ c1p, const float* __restrict__ c1b, const float* __restrict__ c2,
    float* __restrict__ magg, float* __restrict__ xdel) {
    __shared__ unsigned short S[128 * SPAD];   // silu(pre) then mg, bf16; rows wave-private
    __shared__ float cds[NN * 3];
    __shared__ float rad[NN];
    __shared__ float phis[NN];
    __shared__ float red[4 * HID];

    const int i = blockIdx.x;
    const int base = i & ~127;
    const int irel = i & 127;
    const int tid = threadIdx.x;
    const int lane = tid & 63;
    const int wv = tid >> 6;
    const int lc = lane & 15, lg = lane >> 4;
    const int j0 = wv * 32;                    // wave's j-range [j0, j0+32)

    // ---- phase 0: coord diffs + radial ----
    const float xi0 = x[i * 3 + 0], xi1 = x[i * 3 + 1], xi2 = x[i * 3 + 2];
    if (tid < NN) {
        int j = base + tid;
        float d0 = xi0 - x[j * 3 + 0], d1 = xi1 - x[j * 3 + 1], d2 = xi2 - x[j * 3 + 2];
        cds[tid * 3 + 0] = d0; cds[tid * 3 + 1] = d1; cds[tid * 3 + 2] = d2;
        rad[tid] = d0 * d0 + d1 * d1 + d2 * d2;
    }
    __syncthreads();

    // ---- S = silu(pre), wave-private rows [j0, j0+32) ----
    {
        const int bl = lane & 31, bh = lane >> 5;
        const int col0 = bl * 4;
        const float4 p1v = *(const float4*)(p1g + (size_t)i * HID + col0);
        const float4 wrv = *(const float4*)(ew1 + 256 * HID + col0);
        float4 bcv = *(const float4*)(ew1 + 257 * HID + col0);
        const float4 ebv = *(const float4*)(eb1 + col0);
        bcv.x += ebv.x; bcv.y += ebv.y; bcv.z += ebv.z; bcv.w += ebv.w;
#pragma unroll
        for (int it = 0; it < 16; ++it) {
            int row = j0 + it * 2 + bh;
            float rv = rad[row];
            const float4 p2v = *(const float4*)(p2g + (size_t)(base + row) * HID + col0);
            unsigned s0 = f2bf(fsilu(p1v.x + p2v.x + rv * wrv.x + bcv.x));
            unsigned s1 = f2bf(fsilu(p1v.y + p2v.y + rv * wrv.y + bcv.y));
            unsigned s2 = f2bf(fsilu(p1v.z + p2v.z + rv * wrv.z + bcv.z));
            unsigned s3 = f2bf(fsilu(p1v.w + p2v.w + rv * wrv.w + bcv.w));
            uint2 pk; pk.x = s0 | (s1 << 16); pk.y = s2 | (s3 << 16);
            *(uint2*)(S + row * SPAD + col0) = pk;
        }
    }
    // no barrier: rows are wave-private from here on

    // ---- GEMM1: P = W2^T @ S^T ----
    bf16x8 bf[4][2];
#pragma unroll
    for (int kk = 0; kk < 4; ++kk)
#pragma unroll
        for (int jt = 0; jt < 2; ++jt)
            bf[kk][jt] = *(const bf16x8*)&S[(j0 + jt * 16 + lc) * SPAD + kk * 32 + lg * 8];
    f32x4 acc[8][2];
#pragma unroll
    for (int ct = 0; ct < 8; ++ct) { acc[ct][0] = (f32x4){0.f,0.f,0.f,0.f}; acc[ct][1] = (f32x4){0.f,0.f,0.f,0.f}; }
#pragma unroll
    for (int ct = 0; ct < 8; ++ct)
#pragma unroll
        for (int kk = 0; kk < 4; ++kk) {
            bf16x8 a = *(const bf16x8*)(w2p + (size_t)((ct * 4 + kk) * 64 + lane) * 8);
            acc[ct][0] = __builtin_amdgcn_mfma_f32_16x16x32_bf16(a, bf[kk][0], acc[ct][0], 0, 0, 0);
            acc[ct][1] = __builtin_amdgcn_mfma_f32_16x16x32_bf16(a, bf[kk][1], acc[ct][1], 0, 0, 0);
        }

    // ---- epilogue: m = silu(P + b2[c]); att partials per-lane ----
    float patt0 = 0.f, patt1 = 0.f;
#pragma unroll
    for (int ct = 0; ct < 8; ++ct) {
        const float4 b2v = *(const float4*)(b2 + ct * 16 + lg * 4);
        const float4 awv = *(const float4*)(attw + ct * 16 + lg * 4);
        {
            f32x4 a = acc[ct][0];
            float m0 = fsilu(a[0] + b2v.x), m1 = fsilu(a[1] + b2v.y);
            float m2 = fsilu(a[2] + b2v.z), m3 = fsilu(a[3] + b2v.w);
            patt0 += m0 * awv.x + m1 * awv.y + m2 * awv.z + m3 * awv.w;
            acc[ct][0] = (f32x4){m0, m1, m2, m3};
        }
        {
            f32x4 a = acc[ct][1];
            float m0 = fsilu(a[0] + b2v.x), m1 = fsilu(a[1] + b2v.y);
            float m2 = fsilu(a[2] + b2v.z), m3 = fsilu(a[3] + b2v.w);
            patt1 += m0 * awv.x + m1 * awv.y + m2 * awv.z + m3 * awv.w;
            acc[ct][1] = (f32x4){m0, m1, m2, m3};
        }
    }
    patt0 += __shfl_xor(patt0, 16, 64); patt0 += __shfl_xor(patt0, 32, 64);
    patt1 += __shfl_xor(patt1, 16, 64); patt1 += __shfl_xor(patt1, 32, 64);
    const float attb = attbp[0];
    const float gv0 = (j0 + lc == irel) ? 0.f : fsig(patt0 + attb);
    const float gv1 = (j0 + 16 + lc == irel) ? 0.f : fsig(patt1 + attb);

    // ---- mg = gate*m -> S rows (b64 writes, wave-private) ----
#pragma unroll
    for (int ct = 0; ct < 8; ++ct) {
#pragma unroll
        for (int jt = 0; jt < 2; ++jt) {
            float g = jt ? gv1 : gv0;
            f32x4 a = acc[ct][jt];
            unsigned u0 = f2bf(a[0] * g), u1 = f2bf(a[1] * g);
            unsigned u2 = f2bf(a[2] * g), u3 = f2bf(a[3] * g);
            uint2 pk; pk.x = u0 | (u1 << 16); pk.y = u2 | (u3 << 16);
            *(uint2*)(S + (j0 + jt * 16 + lc) * SPAD + ct * 16 + lg * 4) = pk;
        }
    }

    // ---- GEMM2: E2 = C1^T @ mg^T ----
    bf16x8 bg[4][2];
#pragma unroll
    for (int kk = 0; kk < 4; ++kk)
#pragma unroll
        for (int jt = 0; jt < 2; ++jt)
            bg[kk][jt] = *(const bf16x8*)&S[(j0 + jt * 16 + lc) * SPAD + kk * 32 + lg * 8];
    f32x4 acc2[8][2];
#pragma unroll
    for (int ct = 0; ct < 8; ++ct) { acc2[ct][0] = (f32x4){0.f,0.f,0.f,0.f}; acc2[ct][1] = (f32x4){0.f,0.f,0.f,0.f}; }
#pragma unroll
    for (int ct = 0; ct < 8; ++ct)
#pragma unroll
        for (int kk = 0; kk < 4; ++kk) {
            bf16x8 a = *(const bf16x8*)(c1p + (size_t)((ct * 4 + kk) * 64 + lane) * 8);
            acc2[ct][0] = __builtin_amdgcn_mfma_f32_16x16x32_bf16(a, bg[kk][0], acc2[ct][0], 0, 0, 0);
            acc2[ct][1] = __builtin_amdgcn_mfma_f32_16x16x32_bf16(a, bg[kk][1], acc2[ct][1], 0, 0, 0);
        }

    // ---- phi[j] = sum_c' silu(E2 + c1b)*c2, per-lane + 2 shfl ----
    float pp0 = 0.f, pp1 = 0.f;
#pragma unroll
    for (int ct = 0; ct < 8; ++ct) {
        const float4 cbv = *(const float4*)(c1b + ct * 16 + lg * 4);
        const float4 cwv = *(const float4*)(c2 + ct * 16 + lg * 4);
        {
            f32x4 a = acc2[ct][0];
            pp0 += fsilu(a[0] + cbv.x) * cwv.x + fsilu(a[1] + cbv.y) * cwv.y +
                   fsilu(a[2] + cbv.z) * cwv.z + fsilu(a[3] + cbv.w) * cwv.w;
        }
        {
            f32x4 a = acc2[ct][1];
            pp1 += fsilu(a[0] + cbv.x) * cwv.x + fsilu(a[1] + cbv.y) * cwv.y +
                   fsilu(a[2] + cbv.z) * cwv.z + fsilu(a[3] + cbv.w) * cwv.w;
        }
    }
    pp0 += __shfl_xor(pp0, 16, 64); pp0 += __shfl_xor(pp0, 32, 64);
    pp1 += __shfl_xor(pp1, 16, 64); pp1 += __shfl_xor(pp1, 32, 64);
    if (lg == 0) {
        phis[j0 + lc] = pp0;
        phis[j0 + 16 + lc] = pp1;
    }

    // ---- m_agg partial: column-sum of mg over own wave's rows (vectorized) ----
    {
        const int p = tid & 63;     // feature pair: c = 2p, 2p+1
        float s0 = 0.f, s1 = 0.f;
#pragma unroll
        for (int q = 0; q < 32; ++q) {
            unsigned u = *(const unsigned*)(S + (j0 + q) * SPAD + p * 2);
            s0 += bf2f((unsigned short)(u & 0xffffu));
            s1 += bf2f((unsigned short)(u >> 16));
        }
        float2 pr; pr.x = s0; pr.y = s1;
        *(float2*)(red + wv * HID + p * 2) = pr;
    }
    __syncthreads();   // B1: phis + red complete

    if (tid < NN) {
        float ph = phis[tid];
        cds[tid * 3 + 0] *= ph; cds[tid * 3 + 1] *= ph; cds[tid * 3 + 2] *= ph;
    }
    if (tid < HID)
        magg[(size_t)i * HID + tid] = red[tid] + red[HID + tid] + red[2 * HID + tid] + red[3 * HID + tid];
    __syncthreads();   // B2: cds scaled

    if (tid < 192) {
        const int a = tid >> 6, ln = tid & 63;
        float v = cds[ln * 3 + a] + cds[(ln + 64) * 3 + a];
#pragma unroll
        for (int off = 1; off <= 32; off <<= 1) v += __shfl_xor(v, off, 64);
        if (ln == 0) xdel[i * 3 + a] = v * (1.f / 127.f);
    }
}

// ---------------- node update + coord apply ----------------
__global__ void k_node(float* __restrict__ h, float* __restrict__ x,
                       const float* __restrict__ magg, const float* __restrict__ xdel,
                       const float* __restrict__ nw1, const float* __restrict__ nb1,
                       const float* __restrict__ nw2, const float* __restrict__ nb2) {
    __shared__ float hs[HID], ms[HID], dhs[HID];
    int n = blockIdx.x, t = threadIdx.x;
    hs[t] = h[n * HID + t];
    ms[t] = magg[n * HID + t];
    __syncthreads();
    float acc = nb1[t];
#pragma unroll 4
    for (int k = 0; k < HID; ++k)
        acc += hs[k] * nw1[k * HID + t] + ms[k] * nw1[(HID + k) * HID + t];
    dhs[t] = fsilu(acc);
    __syncthreads();
    float a2 = nb2[t];
#pragma unroll 4
    for (int k = 0; k < HID; ++k) a2 += dhs[k] * nw2[k * HID + t];
    h[n * HID + t] = hs[t] + a2;
    if (t < 3) x[n * 3 + t] += xdel[n * 3 + t];
}

// ---------------- output embedding ----------------
__global__ void k_embout(const float* __restrict__ h, const float* __restrict__ w,
                         const float* __restrict__ b, float* __restrict__ hout) {
    __shared__ float hs[HID];
    int n = blockIdx.x, t = threadIdx.x;
    hs[t] = h[n * HID + t];
    __syncthreads();
    float acc = b[t];
#pragma unroll 4
    for (int k = 0; k < HID; ++k) acc += hs[k] * w[k * HID + t];
    hout[n * HID + t] = acc;
}

// ---------------- per-graph mean pool ----------------
__global__ void k_pool(const float* __restrict__ he, float* __restrict__ hp) {
    int gph = blockIdx.x, t = threadIdx.x;
    float s = 0.f;
    for (int j = 0; j < NN; ++j) s += he[(gph * NN + j) * HID + t];
    hp[gph * HID + t] = s * (1.f / 128.f);
}

// ---------------- head MLP ----------------
__global__ void k_head(const float* __restrict__ hp, const float* __restrict__ w1,
                       const float* __restrict__ b1, const float* __restrict__ w2,
                       const float* __restrict__ b2, float* __restrict__ out) {
    __shared__ float hs[HID], rs[HID];
    int gph = blockIdx.x, t = threadIdx.x;
    hs[t] = hp[gph * HID + t];
    __syncthreads();
    float acc = b1[t];
#pragma unroll 4
    for (int k = 0; k < HID; ++k) acc += hs[k] * w1[k * HID + t];
    rs[t] = fmaxf(acc, 0.f);
    __syncthreads();
    if (t < ONF) {
        float a = b2[t];
        for (int k = 0; k < HID; ++k) a += rs[k] * w2[k * ONF + t];
        out[gph * ONF + t] = a;
    }
}

extern "C" void kernel_launch(void* const* d_in, const int* in_sizes, int n_in,
                              void* d_out, int out_size, void* d_ws, size_t ws_size,
                              hipStream_t stream) {
    const float* h0        = (const float*)d_in[0];
    const float* x0        = (const float*)d_in[1];
    const float* emb_in_w  = (const float*)d_in[2];
    const float* emb_in_b  = (const float*)d_in[3];
    const float* edge_w1   = (const float*)d_in[4];
    const float* edge_b1   = (const float*)d_in[5];
    const float* edge_w2   = (const float*)d_in[6];
    const float* edge_b2   = (const float*)d_in[7];
    const float* att_w     = (const float*)d_in[8];
    const float* att_b     = (const float*)d_in[9];
    const float* node_w1   = (const float*)d_in[10];
    const float* node_b1   = (const float*)d_in[11];
    const float* node_w2   = (const float*)d_in[12];
    const float* node_b2   = (const float*)d_in[13];
    const float* coord_w1  = (const float*)d_in[14];
    const float* coord_b1  = (const float*)d_in[15];
    const float* coord_w2  = (const float*)d_in[16];
    const float* emb_out_w = (const float*)d_in[17];
    const float* emb_out_b = (const float*)d_in[18];
    const float* head_w1   = (const float*)d_in[19];
    const float* head_b1   = (const float*)d_in[20];
    const float* head_w2   = (const float*)d_in[21];
    const float* head_b2   = (const float*)d_in[22];

    float* ws    = (float*)d_ws;
    float* h_cur = ws;                   // BN*HID
    float* p1    = h_cur + BN * HID;     // BN*HID (reused as h_emb at the end)
    float* p2    = p1 + BN * HID;        // BN*HID (reused as h_pool at the end)
    float* magg  = p2 + BN * HID;        // BN*HID
    float* xc    = magg + BN * HID;      // BN*3
    float* xdel  = xc + BN * 3;          // BN*3
    unsigned short* wpack = (unsigned short*)(xdel + BN * 3);  // 8 * 16384 bf16

    k_pack<<<64, 256, 0, stream>>>(edge_w2, coord_w1, wpack);
    k_embed<<<BN, HID, 0, stream>>>(h0, x0, emb_in_w, emb_in_b, h_cur, xc);
    for (int l = 0; l < NLAY; ++l) {
        k_proj<<<BN, HID, 0, stream>>>(h_cur, edge_w1 + (size_t)l * 258 * HID, p1, p2);
        k_edge<<<BN, 256, 0, stream>>>(xc, p1, p2,
            edge_w1 + (size_t)l * 258 * HID, edge_b1 + l * HID,
            wpack + (size_t)l * HID * HID, edge_b2 + l * HID,
            att_w + l * HID, att_b + l,
            wpack + (size_t)(4 + l) * HID * HID, coord_b1 + l * HID, coord_w2 + l * HID,
            magg, xdel);
        k_node<<<BN, HID, 0, stream>>>(h_cur, xc, magg, xdel,
            node_w1 + (size_t)l * 2 * HID * HID, node_b1 + l * HID,
            node_w2 + (size_t)l * HID * HID, node_b2 + l * HID);
    }
    k_embout<<<BN, HID, 0, stream>>>(h_cur, emb_out_w, emb_out_b, p1);
    k_pool<<<NB, HID, 0, stream>>>(p1, p2);
    k_head<<<NB, HID, 0, stream>>>(p2, head_w1, head_b1, head_w2, head_b2, (float*)d_out);
}

// Round 4
// 327.720 us; speedup vs baseline: 4.8097x; 1.2623x over previous
//
#include <hip/hip_runtime.h>
#include <math.h>

#define HID 128
#define NN 128      // nodes per graph
#define NB 16       // graphs
#define BN 2048     // total nodes
#define NLAY 4
#define INF 21
#define ONF 20
#define SPAD 136    // padded LDS row stride in bf16 elems

typedef __attribute__((ext_vector_type(8))) short bf16x8;
typedef __attribute__((ext_vector_type(4))) float f32x4;

// hardware reciprocal (~1 ulp) — avoids the precise-div v_div_* sequence
__device__ __forceinline__ float frcp(float x) {
    float r; asm("v_rcp_f32 %0, %1" : "=v"(r) : "v"(x)); return r;
}
__device__ __forceinline__ float fsilu(float v) { return v * frcp(1.f + __expf(-v)); }
__device__ __forceinline__ float fsig(float v)  { return frcp(1.f + __expf(-v)); }
// HW packed f32->bf16 RNE: low16 = cvt(lo), high16 = cvt(hi)
__device__ __forceinline__ unsigned cvtpk_bf16(float lo, float hi) {
    unsigned r; asm("v_cvt_pk_bf16_f32 %0, %1, %2" : "=v"(r) : "v"(lo), "v"(hi)); return r;
}
__device__ __forceinline__ unsigned short f2bf(float f) {   // RNE fp32->bf16 (cold path)
    union { float f; unsigned u; } v; v.f = f;
    unsigned r = v.u + 0x7fffu + ((v.u >> 16) & 1u);
    return (unsigned short)(r >> 16);
}
__device__ __forceinline__ float bf2f(unsigned short u) {
    union { unsigned u; float f; } v; v.u = ((unsigned)u) << 16;
    return v.f;
}

// ---------------- weight pack: 8 matrices (edge_w2 x4, coord_w1 x4) -> bf16 fragments ----------
// entry e: matrix m=e>>11, f=e&2047: n=f>>8 (tile), kk=(f>>6)&3, l=f&63.
// lane l holds W[k=kk*32+(l>>4)*8+j][n*16+(l&15)], j=0..7  == A-fragment of W^T (row-tile n, k-blk kk)
__global__ void k_pack(const float* __restrict__ w2, const float* __restrict__ c1,
                       unsigned short* __restrict__ out) {
    int e = blockIdx.x * 256 + threadIdx.x;   // 64 blocks * 256 = 16384 entries
    int m = e >> 11;
    int f = e & 2047;
    int l = f & 63, kk = (f >> 6) & 3, n = f >> 8;
    const float* w = (m < 4) ? (w2 + (size_t)m * HID * HID) : (c1 + (size_t)(m - 4) * HID * HID);
    int col = n * 16 + (l & 15);
    int k0 = kk * 32 + (l >> 4) * 8;
    unsigned short tmp[8];
#pragma unroll
    for (int j = 0; j < 8; ++j) tmp[j] = f2bf(w[(size_t)(k0 + j) * HID + col]);
    *(bf16x8*)(out + (size_t)e * 8) = *(const bf16x8*)tmp;
}

// ---------------- input embedding ----------------
__global__ void k_embed(const float* __restrict__ h0, const float* __restrict__ x0,
                        const float* __restrict__ w, const float* __restrict__ b,
                        float* __restrict__ h, float* __restrict__ x) {
    __shared__ float hs[INF];
    int n = blockIdx.x, t = threadIdx.x;
    if (t < INF) hs[t] = h0[n * INF + t];
    __syncthreads();
    float acc = b[t];
#pragma unroll
    for (int k = 0; k < INF; ++k) acc += hs[k] * w[k * HID + t];
    h[n * HID + t] = acc;
    if (t < 3) x[n * 3 + t] = x0[n * 3 + t];
}

// ---------------- per-layer node projections: p1 = h@W1a, p2 = h@W1b ----------------
__global__ void k_proj(const float* __restrict__ h, const float* __restrict__ ew1,
                       float* __restrict__ p1, float* __restrict__ p2) {
    __shared__ float hs[HID];
    int n = blockIdx.x, t = threadIdx.x;
    hs[t] = h[n * HID + t];
    __syncthreads();
    float a1 = 0.f, a2 = 0.f;
#pragma unroll 4
    for (int k = 0; k < HID; ++k) {
        float hv = hs[k];
        a1 += hv * ew1[k * HID + t];
        a2 += hv * ew1[(HID + k) * HID + t];
    }
    p1[n * HID + t] = a1;
    p2[n * HID + t] = a2;
}

// ---------------- edge pipeline (swapped-operand MFMA): one block per node i ----------------
__global__ __launch_bounds__(256, 4) void k_edge(
    const float* __restrict__ x, const float* __restrict__ p1g, const float* __restrict__ p2g,
    const float* __restrict__ ew1, const float* __restrict__ eb1,
    const unsigned short* __restrict__ w2p, const float* __restrict__ b2,
    const float* __restrict__ attw, const float* __restrict__ attbp,
    const unsigned short* __restrict__ c1p, const float* __restrict__ c1b, const float* __restrict__ c2,
    float* __restrict__ magg, float* __restrict__ xdel) {
    __shared__ unsigned short S[128 * SPAD];   // silu(pre) then mg, bf16; rows wave-private
    __shared__ float cds[NN * 3];
    __shared__ float rad[NN];
    __shared__ float phis[NN];
    __shared__ float red[4 * HID];

    const int i = blockIdx.x;
    const int base = i & ~127;
    const int irel = i & 127;
    const int tid = threadIdx.x;
    const int lane = tid & 63;
    const int wv = tid >> 6;
    const int lc = lane & 15, lg = lane >> 4;
    const int j0 = wv * 32;                    // wave's j-range [j0, j0+32)

    // ---- phase 0: coord diffs + radial ----
    const float xi0 = x[i * 3 + 0], xi1 = x[i * 3 + 1], xi2 = x[i * 3 + 2];
    if (tid < NN) {
        int j = base + tid;
        float d0 = xi0 - x[j * 3 + 0], d1 = xi1 - x[j * 3 + 1], d2 = xi2 - x[j * 3 + 2];
        cds[tid * 3 + 0] = d0; cds[tid * 3 + 1] = d1; cds[tid * 3 + 2] = d2;
        rad[tid] = d0 * d0 + d1 * d1 + d2 * d2;
    }
    __syncthreads();

    // ---- S = silu(pre), wave-private rows [j0, j0+32) ----
    {
        const int bl = lane & 31, bh = lane >> 5;
        const int col0 = bl * 4;
        const float4 p1v = *(const float4*)(p1g + (size_t)i * HID + col0);
        const float4 wrv = *(const float4*)(ew1 + 256 * HID + col0);
        float4 bcv = *(const float4*)(ew1 + 257 * HID + col0);
        const float4 ebv = *(const float4*)(eb1 + col0);
        // hoist p1 + (w_attr + b1) out of the loop
        bcv.x += ebv.x + p1v.x; bcv.y += ebv.y + p1v.y;
        bcv.z += ebv.z + p1v.z; bcv.w += ebv.w + p1v.w;
#pragma unroll
        for (int it = 0; it < 16; ++it) {
            int row = j0 + it * 2 + bh;
            float rv = rad[row];
            const float4 p2v = *(const float4*)(p2g + (size_t)(base + row) * HID + col0);
            float v0 = fsilu(fmaf(rv, wrv.x, p2v.x + bcv.x));
            float v1 = fsilu(fmaf(rv, wrv.y, p2v.y + bcv.y));
            float v2 = fsilu(fmaf(rv, wrv.z, p2v.z + bcv.z));
            float v3 = fsilu(fmaf(rv, wrv.w, p2v.w + bcv.w));
            uint2 pk; pk.x = cvtpk_bf16(v0, v1); pk.y = cvtpk_bf16(v2, v3);
            *(uint2*)(S + row * SPAD + col0) = pk;
        }
    }
    // no barrier: rows are wave-private from here on

    // ---- GEMM1: P = W2^T @ S^T ----
    bf16x8 bf[4][2];
#pragma unroll
    for (int kk = 0; kk < 4; ++kk)
#pragma unroll
        for (int jt = 0; jt < 2; ++jt)
            bf[kk][jt] = *(const bf16x8*)&S[(j0 + jt * 16 + lc) * SPAD + kk * 32 + lg * 8];
    f32x4 acc[8][2];
#pragma unroll
    for (int ct = 0; ct < 8; ++ct) { acc[ct][0] = (f32x4){0.f,0.f,0.f,0.f}; acc[ct][1] = (f32x4){0.f,0.f,0.f,0.f}; }
#pragma unroll
    for (int ct = 0; ct < 8; ++ct)
#pragma unroll
        for (int kk = 0; kk < 4; ++kk) {
            bf16x8 a = *(const bf16x8*)(w2p + (size_t)((ct * 4 + kk) * 64 + lane) * 8);
            acc[ct][0] = __builtin_amdgcn_mfma_f32_16x16x32_bf16(a, bf[kk][0], acc[ct][0], 0, 0, 0);
            acc[ct][1] = __builtin_amdgcn_mfma_f32_16x16x32_bf16(a, bf[kk][1], acc[ct][1], 0, 0, 0);
        }

    // ---- epilogue: m = silu(P + b2[c]); att partials per-lane ----
    float patt0 = 0.f, patt1 = 0.f;
#pragma unroll
    for (int ct = 0; ct < 8; ++ct) {
        const float4 b2v = *(const float4*)(b2 + ct * 16 + lg * 4);
        const float4 awv = *(const float4*)(attw + ct * 16 + lg * 4);
        {
            f32x4 a = acc[ct][0];
            float m0 = fsilu(a[0] + b2v.x), m1 = fsilu(a[1] + b2v.y);
            float m2 = fsilu(a[2] + b2v.z), m3 = fsilu(a[3] + b2v.w);
            patt0 += m0 * awv.x + m1 * awv.y + m2 * awv.z + m3 * awv.w;
            acc[ct][0] = (f32x4){m0, m1, m2, m3};
        }
        {
            f32x4 a = acc[ct][1];
            float m0 = fsilu(a[0] + b2v.x), m1 = fsilu(a[1] + b2v.y);
            float m2 = fsilu(a[2] + b2v.z), m3 = fsilu(a[3] + b2v.w);
            patt1 += m0 * awv.x + m1 * awv.y + m2 * awv.z + m3 * awv.w;
            acc[ct][1] = (f32x4){m0, m1, m2, m3};
        }
    }
    patt0 += __shfl_xor(patt0, 16, 64); patt0 += __shfl_xor(patt0, 32, 64);
    patt1 += __shfl_xor(patt1, 16, 64); patt1 += __shfl_xor(patt1, 32, 64);
    const float attb = attbp[0];
    const float gv0 = (j0 + lc == irel) ? 0.f : fsig(patt0 + attb);
    const float gv1 = (j0 + 16 + lc == irel) ? 0.f : fsig(patt1 + attb);

    // ---- mg = gate*m -> S rows (b64 writes, wave-private) ----
#pragma unroll
    for (int ct = 0; ct < 8; ++ct) {
#pragma unroll
        for (int jt = 0; jt < 2; ++jt) {
            float g = jt ? gv1 : gv0;
            f32x4 a = acc[ct][jt];
            uint2 pk;
            pk.x = cvtpk_bf16(a[0] * g, a[1] * g);
            pk.y = cvtpk_bf16(a[2] * g, a[3] * g);
            *(uint2*)(S + (j0 + jt * 16 + lc) * SPAD + ct * 16 + lg * 4) = pk;
        }
    }

    // ---- GEMM2: E2 = C1^T @ mg^T ----
    bf16x8 bg[4][2];
#pragma unroll
    for (int kk = 0; kk < 4; ++kk)
#pragma unroll
        for (int jt = 0; jt < 2; ++jt)
            bg[kk][jt] = *(const bf16x8*)&S[(j0 + jt * 16 + lc) * SPAD + kk * 32 + lg * 8];
    f32x4 acc2[8][2];
#pragma unroll
    for (int ct = 0; ct < 8; ++ct) { acc2[ct][0] = (f32x4){0.f,0.f,0.f,0.f}; acc2[ct][1] = (f32x4){0.f,0.f,0.f,0.f}; }
#pragma unroll
    for (int ct = 0; ct < 8; ++ct)
#pragma unroll
        for (int kk = 0; kk < 4; ++kk) {
            bf16x8 a = *(const bf16x8*)(c1p + (size_t)((ct * 4 + kk) * 64 + lane) * 8);
            acc2[ct][0] = __builtin_amdgcn_mfma_f32_16x16x32_bf16(a, bg[kk][0], acc2[ct][0], 0, 0, 0);
            acc2[ct][1] = __builtin_amdgcn_mfma_f32_16x16x32_bf16(a, bg[kk][1], acc2[ct][1], 0, 0, 0);
        }

    // ---- phi[j] = sum_c' silu(E2 + c1b)*c2, per-lane + 2 shfl ----
    float pp0 = 0.f, pp1 = 0.f;
#pragma unroll
    for (int ct = 0; ct < 8; ++ct) {
        const float4 cbv = *(const float4*)(c1b + ct * 16 + lg * 4);
        const float4 cwv = *(const float4*)(c2 + ct * 16 + lg * 4);
        {
            f32x4 a = acc2[ct][0];
            pp0 += fsilu(a[0] + cbv.x) * cwv.x + fsilu(a[1] + cbv.y) * cwv.y +
                   fsilu(a[2] + cbv.z) * cwv.z + fsilu(a[3] + cbv.w) * cwv.w;
        }
        {
            f32x4 a = acc2[ct][1];
            pp1 += fsilu(a[0] + cbv.x) * cwv.x + fsilu(a[1] + cbv.y) * cwv.y +
                   fsilu(a[2] + cbv.z) * cwv.z + fsilu(a[3] + cbv.w) * cwv.w;
        }
    }
    pp0 += __shfl_xor(pp0, 16, 64); pp0 += __shfl_xor(pp0, 32, 64);
    pp1 += __shfl_xor(pp1, 16, 64); pp1 += __shfl_xor(pp1, 32, 64);
    if (lg == 0) {
        phis[j0 + lc] = pp0;
        phis[j0 + 16 + lc] = pp1;
    }

    // ---- m_agg partial: column-sum of mg over own wave's rows (vectorized) ----
    {
        const int p = tid & 63;     // feature pair: c = 2p, 2p+1
        float s0 = 0.f, s1 = 0.f;
#pragma unroll
        for (int q = 0; q < 32; ++q) {
            unsigned u = *(const unsigned*)(S + (j0 + q) * SPAD + p * 2);
            s0 += bf2f((unsigned short)(u & 0xffffu));
            s1 += bf2f((unsigned short)(u >> 16));
        }
        float2 pr; pr.x = s0; pr.y = s1;
        *(float2*)(red + wv * HID + p * 2) = pr;
    }
    __syncthreads();   // B1: phis + red complete

    if (tid < NN) {
        float ph = phis[tid];
        cds[tid * 3 + 0] *= ph; cds[tid * 3 + 1] *= ph; cds[tid * 3 + 2] *= ph;
    }
    if (tid < HID)
        magg[(size_t)i * HID + tid] = red[tid] + red[HID + tid] + red[2 * HID + tid] + red[3 * HID + tid];
    __syncthreads();   // B2: cds scaled

    if (tid < 192) {
        const int a = tid >> 6, ln = tid & 63;
        float v = cds[ln * 3 + a] + cds[(ln + 64) * 3 + a];
#pragma unroll
        for (int off = 1; off <= 32; off <<= 1) v += __shfl_xor(v, off, 64);
        if (ln == 0) xdel[i * 3 + a] = v * (1.f / 127.f);
    }
}

// ---------------- node update + coord apply ----------------
__global__ void k_node(float* __restrict__ h, float* __restrict__ x,
                       const float* __restrict__ magg, const float* __restrict__ xdel,
                       const float* __restrict__ nw1, const float* __restrict__ nb1,
                       const float* __restrict__ nw2, const float* __restrict__ nb2) {
    __shared__ float hs[HID], ms[HID], dhs[HID];
    int n = blockIdx.x, t = threadIdx.x;
    hs[t] = h[n * HID + t];
    ms[t] = magg[n * HID + t];
    __syncthreads();
    float acc = nb1[t];
#pragma unroll 4
    for (int k = 0; k < HID; ++k)
        acc += hs[k] * nw1[k * HID + t] + ms[k] * nw1[(HID + k) * HID + t];
    dhs[t] = fsilu(acc);
    __syncthreads();
    float a2 = nb2[t];
#pragma unroll 4
    for (int k = 0; k < HID; ++k) a2 += dhs[k] * nw2[k * HID + t];
    h[n * HID + t] = hs[t] + a2;
    if (t < 3) x[n * 3 + t] += xdel[n * 3 + t];
}

// ---------------- output embedding ----------------
__global__ void k_embout(const float* __restrict__ h, const float* __restrict__ w,
                         const float* __restrict__ b, float* __restrict__ hout) {
    __shared__ float hs[HID];
    int n = blockIdx.x, t = threadIdx.x;
    hs[t] = h[n * HID + t];
    __syncthreads();
    float acc = b[t];
#pragma unroll 4
    for (int k = 0; k < HID; ++k) acc += hs[k] * w[k * HID + t];
    hout[n * HID + t] = acc;
}

// ---------------- per-graph mean pool ----------------
__global__ void k_pool(const float* __restrict__ he, float* __restrict__ hp) {
    int gph = blockIdx.x, t = threadIdx.x;
    float s = 0.f;
    for (int j = 0; j < NN; ++j) s += he[(gph * NN + j) * HID + t];
    hp[gph * HID + t] = s * (1.f / 128.f);
}

// ---------------- head MLP ----------------
__global__ void k_head(const float* __restrict__ hp, const float* __restrict__ w1,
                       const float* __restrict__ b1, const float* __restrict__ w2,
                       const float* __restrict__ b2, float* __restrict__ out) {
    __shared__ float hs[HID], rs[HID];
    int gph = blockIdx.x, t = threadIdx.x;
    hs[t] = hp[gph * HID + t];
    __syncthreads();
    float acc = b1[t];
#pragma unroll 4
    for (int k = 0; k < HID; ++k) acc += hs[k] * w1[k * HID + t];
    rs[t] = fmaxf(acc, 0.f);
    __syncthreads();
    if (t < ONF) {
        float a = b2[t];
        for (int k = 0; k < HID; ++k) a += rs[k] * w2[k * ONF + t];
        out[gph * ONF + t] = a;
    }
}

extern "C" void kernel_launch(void* const* d_in, const int* in_sizes, int n_in,
                              void* d_out, int out_size, void* d_ws, size_t ws_size,
                              hipStream_t stream) {
    const float* h0        = (const float*)d_in[0];
    const float* x0        = (const float*)d_in[1];
    const float* emb_in_w  = (const float*)d_in[2];
    const float* emb_in_b  = (const float*)d_in[3];
    const float* edge_w1   = (const float*)d_in[4];
    const float* edge_b1   = (const float*)d_in[5];
    const float* edge_w2   = (const float*)d_in[6];
    const float* edge_b2   = (const float*)d_in[7];
    const float* att_w     = (const float*)d_in[8];
    const float* att_b     = (const float*)d_in[9];
    const float* node_w1   = (const float*)d_in[10];
    const float* node_b1   = (const float*)d_in[11];
    const float* node_w2   = (const float*)d_in[12];
    const float* node_b2   = (const float*)d_in[13];
    const float* coord_w1  = (const float*)d_in[14];
    const float* coord_b1  = (const float*)d_in[15];
    const float* coord_w2  = (const float*)d_in[16];
    const float* emb_out_w = (const float*)d_in[17];
    const float* emb_out_b = (const float*)d_in[18];
    const float* head_w1   = (const float*)d_in[19];
    const float* head_b1   = (const float*)d_in[20];
    const float* head_w2   = (const float*)d_in[21];
    const float* head_b2   = (const float*)d_in[22];

    float* ws    = (float*)d_ws;
    float* h_cur = ws;                   // BN*HID
    float* p1    = h_cur + BN * HID;     // BN*HID (reused as h_emb at the end)
    float* p2    = p1 + BN * HID;        // BN*HID (reused as h_pool at the end)
    float* magg  = p2 + BN * HID;        // BN*HID
    float* xc    = magg + BN * HID;      // BN*3
    float* xdel  = xc + BN * 3;          // BN*3
    unsigned short* wpack = (unsigned short*)(xdel + BN * 3);  // 8 * 16384 bf16

    k_pack<<<64, 256, 0, stream>>>(edge_w2, coord_w1, wpack);
    k_embed<<<BN, HID, 0, stream>>>(h0, x0, emb_in_w, emb_in_b, h_cur, xc);
    for (int l = 0; l < NLAY; ++l) {
        k_proj<<<BN, HID, 0, stream>>>(h_cur, edge_w1 + (size_t)l * 258 * HID, p1, p2);
        k_edge<<<BN, 256, 0, stream>>>(xc, p1, p2,
            edge_w1 + (size_t)l * 258 * HID, edge_b1 + l * HID,
            wpack + (size_t)l * HID * HID, edge_b2 + l * HID,
            att_w + l * HID, att_b + l,
            wpack + (size_t)(4 + l) * HID * HID, coord_b1 + l * HID, coord_w2 + l * HID,
            magg, xdel);
        k_node<<<BN, HID, 0, stream>>>(h_cur, xc, magg, xdel,
            node_w1 + (size_t)l * 2 * HID * HID, node_b1 + l * HID,
            node_w2 + (size_t)l * HID * HID, node_b2 + l * HID);
    }
    k_embout<<<BN, HID, 0, stream>>>(h_cur, emb_out_w, emb_out_b, p1);
    k_pool<<<NB, HID, 0, stream>>>(p1, p2);
    k_head<<<NB, HID, 0, stream>>>(p2, head_w1, head_b1, head_w2, head_b2, (float*)d_out);
}